// Round 17
// baseline (52.412 us; speedup 1.0000x reference)
//
#include <hip/hip_runtime.h>

#define HH 512
#define WW 512
#define NB 16
#define NTOT (NB * 3 * HH * WW)     // 12582912
#define CHS (HH * WW)               // 262144, CHS % 3 == 1

// 4-wide x 8-tall strips, no LDS (except reduction). Rolling 2-row history.
// R17: dyn<1>+dyn<2> packed over DY via VOP3P v_pk_*_f32. Base rows stored
// interleaved as float2 (slotX=even-stash, slotY=odd-stash); neighbor yc[k]
// broadcast via op_sel (parity of k is compile-time). exp + accumulate stay
// scalar on pair halves. L-const pair swaps per A/B body handle slot roles.
// ycc 5-tap rotated-coef (R8); exp-folded norm consts (R10); unaligned o
// loads (R16). KEEP rolled loop (R6), VGPR <= 128 (R9/R11/R13/R15),
// 512 blocks / 2 waves per SIMD (R12, R7).

#define SC2 (-0.0072134752044448f)  // -1/(2*sigma^2) * log2(e), sigma=10

#if __has_builtin(__builtin_amdgcn_exp2f)
#define EXP2(v) __builtin_amdgcn_exp2f(v)
#else
#define EXP2(v) exp2f(v)
#endif

// ---- VOP3P packed f32 helpers (gfx90a+: v_pk_add/mul/fma_f32) ----
__device__ __forceinline__ float2 pk_add(float2 a, float2 b) {
    float2 d;
    asm("v_pk_add_f32 %0, %1, %2" : "=v"(d) : "v"(a), "v"(b));
    return d;
}
__device__ __forceinline__ float2 pk_mul(float2 a, float2 b) {
    float2 d;
    asm("v_pk_mul_f32 %0, %1, %2" : "=v"(d) : "v"(a), "v"(b));
    return d;
}
__device__ __forceinline__ float2 pk_fma(float2 a, float2 b, float2 c) {
    float2 d;
    asm("v_pk_fma_f32 %0, %1, %2, %3" : "=v"(d) : "v"(a), "v"(b), "v"(c));
    return d;
}
// broadcast half H of a, minus both halves of b:  d = a[H] - b
template<int H>
__device__ __forceinline__ float2 pk_bsub(float2 a, float2 b) {
    float2 d;
    if constexpr (H == 0)
        asm("v_pk_add_f32 %0, %1, %2 op_sel:[0,0] op_sel_hi:[0,1] neg_lo:[0,1] neg_hi:[0,1]"
            : "=v"(d) : "v"(a), "v"(b));
    else
        asm("v_pk_add_f32 %0, %1, %2 op_sel:[1,0] op_sel_hi:[1,1] neg_lo:[0,1] neg_hi:[0,1]"
            : "=v"(d) : "v"(a), "v"(b));
    return d;
}

#define YCH(A, c, k) ((k) & 1 ? A[c][(k) >> 1].y : A[c][(k) >> 1].x)

__device__ __forceinline__ int mod3s(int v) { return v >= 3 ? v - 3 : v; }

__device__ __forceinline__ void build_rot(int mrow, float (&Rc)[3][5], float (&Rb)[3])
{
    constexpr float T[3][5] = {
        { 0.f,     0.f,     0.257f, 0.564f, 0.098f },   // j=0
        { 0.f,    -0.148f, -0.291f, 0.439f, 0.f    },   // j=1
        { 0.439f, -0.368f, -0.071f, 0.f,    0.f    } }; // j=2
    constexpr float Tb[3] = { 16.f/255.f, 128.f/255.f, 128.f/255.f };
    const bool is1 = (mrow == 1);
    const bool is2 = (mrow == 2);
#pragma unroll
    for (int p = 0; p < 3; ++p) {
#pragma unroll
        for (int s = 0; s < 5; ++s) {
            const float v0 = T[p][s], v1 = T[(p+1)%3][s], v2 = T[(p+2)%3][s];
            Rc[p][s] = is1 ? v1 : (is2 ? v2 : v0);
        }
        Rb[p] = is1 ? Tb[(p+1)%3] : (is2 ? Tb[(p+2)%3] : Tb[p]);
    }
}

template<bool EDGE>
__device__ __forceinline__ void load_make(const float* __restrict__ x,
                                          const float* __restrict__ op,
                                          int fbase,
                                          const float (&Rc)[3][5], const float (&Rb)[3],
                                          float2 (&yc2)[3][4], float2 (&oc2)[3][4])
{
#pragma unroll
    for (int c = 0; c < 3; ++c) {
        const int fb = fbase + c * CHS;
        int f0 = fb, f1 = fb + 4, f2 = fb + 8;
        int g0 = fb + 2, g1 = fb + 6;              // o window: 2 unaligned chunks
        if (EDGE) {
            f0 = min(max(f0, 0), NTOT - 4);
            f1 = min(max(f1, 0), NTOT - 4);
            f2 = min(max(f2, 0), NTOT - 4);
            g0 = min(max(g0, 0), NTOT - 4);
            g1 = min(max(g1, 0), NTOT - 4);
        }
        float xw[12], ow[8];
        *(float4*)&xw[0] = *(const float4*)(x + f0);
        *(float4*)&xw[4] = *(const float4*)(x + f1);
        *(float4*)&xw[8] = *(const float4*)(x + f2);
        *(float4*)&ow[0] = *(const float4*)(op + g0);
        *(float4*)&ow[4] = *(const float4*)(op + g1);
#pragma unroll
        for (int k = 0; k < 8; ++k) {
            const int q = (c + k + 2) % 3;         // static after unroll
            float a = Rb[q];
#pragma unroll
            for (int s = 0; s < 5; ++s)
                a = fmaf(xw[k + s], Rc[q][s], a);
            if (k & 1) { yc2[c][k >> 1].y = a; oc2[c][k >> 1].y = ow[k]; }
            else       { yc2[c][k >> 1].x = a; oc2[c][k >> 1].x = ow[k]; }
        }
    }
}

// stash own pixels (window k=p+2) into slot half X (even rows) or Y (odd rows)
template<int HALF>
__device__ __forceinline__ void stash(float2 (&ypd)[3][4], float2 (&obd)[3][4],
                                      const float2 (&yc2)[3][4], const float2 (&oc2)[3][4])
{
#pragma unroll
    for (int c = 0; c < 3; ++c)
#pragma unroll
        for (int p = 0; p < 4; ++p) {
            const float yv = YCH(yc2, c, p + 2);
            const float ov = YCH(oc2, c, p + 2);
            if constexpr (HALF == 0) { ypd[c][p].x = yv; obd[c][p].x = ov; }
            else                     { ypd[c][p].y = yv; obd[c][p].y = ov; }
        }
}

template<bool EDGE>
__device__ __forceinline__ void pairs_dy0(const float2 (&yc2)[3][4], const float2 (&oc2)[3][4],
                                          const bool (&cv)[8], float& acc)
{
    constexpr float L0[3] = { 0.f, -20.99717945f, -20.99435343f }; // [adx]
#pragma unroll
    for (int dx = 1; dx <= 2; ++dx) {
        const float L = L0[dx];
#pragma unroll
        for (int p = 0; p < 4; ++p) {
            const int k = p + dx + 2, kb = p + 2;
            const float d0 = YCH(yc2, 0, k) - YCH(yc2, 0, kb);
            const float d1 = YCH(yc2, 1, k) - YCH(yc2, 1, kb);
            const float d2 = YCH(yc2, 2, k) - YCH(yc2, 2, kb);
            const float ss = fmaf(d2, d2, fmaf(d1, d1, d0 * d0));
            const float sad = fabsf(YCH(oc2, 0, k) - YCH(oc2, 0, kb))
                            + fabsf(YCH(oc2, 1, k) - YCH(oc2, 1, kb))
                            + fabsf(YCH(oc2, 2, k) - YCH(oc2, 2, kb));
            const float sadm = (!EDGE || cv[k]) ? sad : 0.f;
            acc = fmaf(EXP2(fmaf(SC2, ss, L)), sadm, acc);
        }
    }
}

// packed: both dy base rows at once. SWAP=true: slotX=dy2,slotY=dy1 (A body);
// SWAP=false: slotX=dy1,slotY=dy2 (B body).
template<bool EDGE, bool SWAP>
__device__ __forceinline__ void pairs_dyn_pk(const float2 (&yc2)[3][4], const float2 (&oc2)[3][4],
                                             const float2 (&ypd)[3][4], const float2 (&obd)[3][4],
                                             const bool (&cv)[8], float& accL, float& accH)
{
    constexpr float L1v[3] = { -20.99717945f, -20.99435890f, -20.99153288f }; // dy=1,[adx]
    constexpr float L2v[3] = { -20.99435343f, -20.99153288f, -20.98870686f }; // dy=2,[adx]
    const float2 SC2p = make_float2(SC2, SC2);
#pragma unroll
    for (int dx = -2; dx <= 2; ++dx) {
        const int adx = dx < 0 ? -dx : dx;
        const float2 Lp = SWAP ? make_float2(L2v[adx], L1v[adx])
                               : make_float2(L1v[adx], L2v[adx]);
#pragma unroll
        for (int p = 0; p < 4; ++p) {
            const int k = p + dx + 2;              // 0..7, compile-time
            constexpr auto bs = [] {};
            float2 dy0_, dy1_, dy2_, oo0, oo1, oo2;
            if constexpr (true) {
                if ((k & 1) == 0) {
                    dy0_ = pk_bsub<0>(yc2[0][k >> 1], ypd[0][p]);
                    dy1_ = pk_bsub<0>(yc2[1][k >> 1], ypd[1][p]);
                    dy2_ = pk_bsub<0>(yc2[2][k >> 1], ypd[2][p]);
                    oo0  = pk_bsub<0>(oc2[0][k >> 1], obd[0][p]);
                    oo1  = pk_bsub<0>(oc2[1][k >> 1], obd[1][p]);
                    oo2  = pk_bsub<0>(oc2[2][k >> 1], obd[2][p]);
                } else {
                    dy0_ = pk_bsub<1>(yc2[0][k >> 1], ypd[0][p]);
                    dy1_ = pk_bsub<1>(yc2[1][k >> 1], ypd[1][p]);
                    dy2_ = pk_bsub<1>(yc2[2][k >> 1], ypd[2][p]);
                    oo0  = pk_bsub<1>(oc2[0][k >> 1], obd[0][p]);
                    oo1  = pk_bsub<1>(oc2[1][k >> 1], obd[1][p]);
                    oo2  = pk_bsub<1>(oc2[2][k >> 1], obd[2][p]);
                }
            }
            (void)bs;
            float2 ss = pk_mul(dy0_, dy0_);
            ss = pk_fma(dy1_, dy1_, ss);
            ss = pk_fma(dy2_, dy2_, ss);
            const float2 ea = pk_fma(SC2p, ss, Lp);
            // sad per half: abs folds into v_add input modifiers
            float sadL = fabsf(oo0.x) + fabsf(oo1.x) + fabsf(oo2.x);
            float sadH = fabsf(oo0.y) + fabsf(oo1.y) + fabsf(oo2.y);
            if (EDGE && !cv[k]) { sadL = 0.f; sadH = 0.f; }
            accL = fmaf(EXP2(ea.x), sadL, accL);
            accH = fmaf(EXP2(ea.y), sadH, accH);
        }
    }
}

// scalar fallback: single dy, base from slot half H
template<int DY, int H, bool EDGE>
__device__ __forceinline__ void pairs_dyn_sc(const float2 (&yc2)[3][4], const float2 (&oc2)[3][4],
                                             const float2 (&ypd)[3][4], const float2 (&obd)[3][4],
                                             const bool (&cv)[8], float& acc)
{
    constexpr float L1v[3] = { -20.99717945f, -20.99435890f, -20.99153288f };
    constexpr float L2v[3] = { -20.99435343f, -20.99153288f, -20.98870686f };
#pragma unroll
    for (int dx = -2; dx <= 2; ++dx) {
        const int adx = dx < 0 ? -dx : dx;
        const float L = (DY == 1) ? L1v[adx] : L2v[adx];
#pragma unroll
        for (int p = 0; p < 4; ++p) {
            const int k = p + dx + 2;
            const float yb0 = (H == 0) ? ypd[0][p].x : ypd[0][p].y;
            const float yb1 = (H == 0) ? ypd[1][p].x : ypd[1][p].y;
            const float yb2 = (H == 0) ? ypd[2][p].x : ypd[2][p].y;
            const float ob0 = (H == 0) ? obd[0][p].x : obd[0][p].y;
            const float ob1 = (H == 0) ? obd[1][p].x : obd[1][p].y;
            const float ob2 = (H == 0) ? obd[2][p].x : obd[2][p].y;
            const float d0 = YCH(yc2, 0, k) - yb0;
            const float d1 = YCH(yc2, 1, k) - yb1;
            const float d2 = YCH(yc2, 2, k) - yb2;
            const float ss = fmaf(d2, d2, fmaf(d1, d1, d0 * d0));
            const float sad = fabsf(YCH(oc2, 0, k) - ob0)
                            + fabsf(YCH(oc2, 1, k) - ob1)
                            + fabsf(YCH(oc2, 2, k) - ob2);
            const float sadm = (!EDGE || cv[k]) ? sad : 0.f;
            acc = fmaf(EXP2(fmaf(SC2, ss, L)), sadm, acc);
        }
    }
}

template<bool EDGE>
__device__ __forceinline__ float run_strip(const float* __restrict__ x,
                                           const float* __restrict__ op,
                                           int wq, int rb, int b)
{
    bool cv[8];
#pragma unroll
    for (int k = 0; k < 8; ++k) cv[k] = !EDGE || ((unsigned)(wq - 2 + k) < (unsigned)WW);

    const int fb0 = (b * 3 * HH + rb) * WW + (wq - 4);   // c=0, s=0 window base
    int mrow = (2 * rb + wq + 2) % 3;                    // fb0 % 3 (nonneg form)

    float Rc[3][5], Rb[3];
    float2 ypd[3][4], obd[3][4];   // interleaved base pairs (.x=even stash, .y=odd)
    float2 yc2[3][4], oc2[3][4];   // current row as k-pairs
    float accL = 0.f, accH = 0.f;

    // ---- s = 0 ----
    build_rot(mrow, Rc, Rb);
    load_make<EDGE>(x, op, fb0, Rc, Rb, yc2, oc2);
    pairs_dy0<EDGE>(yc2, oc2, cv, accL);
    stash<0>(ypd, obd, yc2, oc2);
    // ---- s = 1 ----
    mrow = mod3s(mrow + 2);
    build_rot(mrow, Rc, Rb);
    load_make<EDGE>(x, op, fb0 + WW, Rc, Rb, yc2, oc2);
    pairs_dy0<EDGE>(yc2, oc2, cv, accL);
    pairs_dyn_sc<1, 0, EDGE>(yc2, oc2, ypd, obd, cv, accH);   // base row 0 (.x)
    stash<1>(ypd, obd, yc2, oc2);

#pragma unroll 1
    for (int s = 2; s < 10; s += 2) {
        // ---- row A = s: .x holds s-2 (dy2), .y holds s-1 (dy1) -> SWAP=true ----
        mrow = mod3s(mrow + 2);
        build_rot(mrow, Rc, Rb);
        const bool rokA = !EDGE || (rb + s) < HH;
        load_make<EDGE>(x, op, fb0 + s * WW, Rc, Rb, yc2, oc2);
        if (s < 8) pairs_dy0<EDGE>(yc2, oc2, cv, accL);
        if (rokA)
            pairs_dyn_pk<EDGE, true>(yc2, oc2, ypd, obd, cv, accL, accH);
        if (s < 8) stash<0>(ypd, obd, yc2, oc2);
        // ---- row B = s+1: .x holds s (dy1), .y holds s-1 (dy2) -> SWAP=false ----
        mrow = mod3s(mrow + 2);
        build_rot(mrow, Rc, Rb);
        const bool rokB = !EDGE || (rb + s + 1) < HH;
        load_make<EDGE>(x, op, fb0 + (s + 1) * WW, Rc, Rb, yc2, oc2);
        if (s + 1 < 8) pairs_dy0<EDGE>(yc2, oc2, cv, accL);
        if (rokB) {
            if (s < 8) pairs_dyn_pk<EDGE, false>(yc2, oc2, ypd, obd, cv, accL, accH);
            else       pairs_dyn_sc<2, 1, EDGE>(yc2, oc2, ypd, obd, cv, accH); // base row 7 (.y)
        }
        if (s + 1 < 8) stash<1>(ypd, obd, yc2, oc2);
    }

    return accL + accH;
}

__global__ __launch_bounds__(256)
void smooth_loss_kernel(const float* __restrict__ x, const float* __restrict__ op,
                        float* __restrict__ total)
{
    const int tx  = threadIdx.x;                    // 0..31
    const int ty  = threadIdx.y;                    // 0..7
    const int tid = ty * 32 + tx;
    const int bx  = blockIdx.x, by = blockIdx.y, b = blockIdx.z;
    const int wq  = bx * 128 + 4 * tx;              // first owned col
    const int rb  = by * 64 + 8 * ty;               // first owned row (<= 504)

    // interior blocks (44%): windows never touch image edges -> no clamps/selects
    float acc;
    if ((bx == 1 || bx == 2) && by < 7)             // block-uniform branch
        acc = run_strip<false>(x, op, wq, rb, b);
    else
        acc = run_strip<true>(x, op, wq, rb, b);

    // ---- reduction: wave shuffle -> LDS -> one atomic per block ----
#pragma unroll
    for (int off = 32; off > 0; off >>= 1)
        acc += __shfl_down(acc, off, 64);

    __shared__ float s_part[4];
    if ((tid & 63) == 0) s_part[tid >> 6] = acc;
    __syncthreads();
    if (tid == 0)
        atomicAdd(total, s_part[0] + s_part[1] + s_part[2] + s_part[3]);
}

extern "C" void kernel_launch(void* const* d_in, const int* in_sizes, int n_in,
                              void* d_out, int out_size, void* d_ws, size_t ws_size,
                              hipStream_t stream) {
    const float* x  = (const float*)d_in[0];   // "input"  [16,3,512,512] fp32
    const float* op = (const float*)d_in[1];   // "output" [16,3,512,512] fp32
    float* total = (float*)d_out;              // scalar fp32

    hipMemsetAsync(total, 0, sizeof(float), stream);

    dim3 grid(4, 8, NB);                       // 512 blocks (2/CU)
    dim3 block(32, 8);                         // 256 threads; strip 4x8 each
    smooth_loss_kernel<<<grid, block, 0, stream>>>(x, op, total);
}

// Round 18
// 45.374 us; speedup vs baseline: 1.1551x; 1.1551x over previous
//
#include <hip/hip_runtime.h>

#define HH 512
#define WW 512
#define NB 16
#define NTOT (NB * 3 * HH * WW)     // 12582912
#define CHS (HH * WW)               // 262144, CHS % 3 == 1

// FINAL (= R16, best measured: 45.5 us, VGPR 124, absmax 0.0).
// 4-wide x 8-tall strips, no LDS (except reduction). Rolling 2-row history.
// ycc[f] = x[f-j]*mat[0][j] + x[f-j+1]*mat[1][j] + x[f-j+2]*mat[2][j] + bias[j],
// j = f % 3 (reference's reshape(-1,3) @ mat over flat NCHW memory).
// 5-tap rotated-coef scheme (R8) + exp-folded norm consts (R10) + unaligned
// o-window loads (R16: 15 VMEM/row).
// 12 unique offsets, each counted twice in the reference -> factor 2 (in L*).
// Ledger of closed doors (do NOT retry):
//  - full unroll (R6: 256 VGPR, spills), reg prefetch (R11: 144 VGPR),
//    5-way mode split (R9: 132), lane-share shuffles (R13: 132),
//    global_load_lds pipelines (R14/R15: 132/136 + compiler vmcnt drain),
//    inline-asm VOP3P packing (R17: 152) -- ALL die at the 128-VGPR cliff.
//  - TLP: 2 waves/SIMD needed (R12), 4 adds nothing (R7).
//  - instruction cuts below ~2%/round are invisible (R10/R16 ~neutral).

#define SC2 (-0.0072134752044448f)  // -1/(2*sigma^2) * log2(e), sigma=10

#if __has_builtin(__builtin_amdgcn_exp2f)
#define EXP2(v) __builtin_amdgcn_exp2f(v)
#else
#define EXP2(v) exp2f(v)
#endif

__device__ __forceinline__ int mod3s(int v) { return v >= 3 ? v - 3 : v; }

__device__ __forceinline__ void build_rot(int mrow, float (&Rc)[3][5], float (&Rb)[3])
{
    constexpr float T[3][5] = {
        { 0.f,     0.f,     0.257f, 0.564f, 0.098f },   // j=0
        { 0.f,    -0.148f, -0.291f, 0.439f, 0.f    },   // j=1
        { 0.439f, -0.368f, -0.071f, 0.f,    0.f    } }; // j=2
    constexpr float Tb[3] = { 16.f/255.f, 128.f/255.f, 128.f/255.f };
    const bool is1 = (mrow == 1);
    const bool is2 = (mrow == 2);
#pragma unroll
    for (int p = 0; p < 3; ++p) {
#pragma unroll
        for (int s = 0; s < 5; ++s) {
            const float v0 = T[p][s], v1 = T[(p+1)%3][s], v2 = T[(p+2)%3][s];
            Rc[p][s] = is1 ? v1 : (is2 ? v2 : v0);
        }
        Rb[p] = is1 ? Tb[(p+1)%3] : (is2 ? Tb[(p+2)%3] : Tb[p]);
    }
}

template<bool EDGE>
__device__ __forceinline__ void load_make(const float* __restrict__ x,
                                          const float* __restrict__ op,
                                          int fbase,
                                          const float (&Rc)[3][5], const float (&Rb)[3],
                                          float (&yc)[3][8], float (&oc)[3][8])
{
#pragma unroll
    for (int c = 0; c < 3; ++c) {
        const int fb = fbase + c * CHS;
        int f0 = fb, f1 = fb + 4, f2 = fb + 8;
        int g0 = fb + 2, g1 = fb + 6;              // o window: 2 unaligned chunks
        if (EDGE) {
            f0 = min(max(f0, 0), NTOT - 4);
            f1 = min(max(f1, 0), NTOT - 4);
            f2 = min(max(f2, 0), NTOT - 4);
            g0 = min(max(g0, 0), NTOT - 4);
            g1 = min(max(g1, 0), NTOT - 4);
        }
        float xw[12], ow[8];
        *(float4*)&xw[0] = *(const float4*)(x + f0);
        *(float4*)&xw[4] = *(const float4*)(x + f1);
        *(float4*)&xw[8] = *(const float4*)(x + f2);
        *(float4*)&ow[0] = *(const float4*)(op + g0);
        *(float4*)&ow[4] = *(const float4*)(op + g1);
#pragma unroll
        for (int k = 0; k < 8; ++k) {
            const int q = (c + k + 2) % 3;         // static after unroll
            float a = Rb[q];
#pragma unroll
            for (int s = 0; s < 5; ++s)
                a = fmaf(xw[k + s], Rc[q][s], a);
            yc[c][k] = a;
            oc[c][k] = ow[k];                      // window col k+2 == ow[k]
        }
    }
}

__device__ __forceinline__ void stash(float (&yb)[3][4], float (&ob)[3][4],
                                      const float (&yc)[3][8], const float (&oc)[3][8])
{
#pragma unroll
    for (int c = 0; c < 3; ++c)
#pragma unroll
        for (int p = 0; p < 4; ++p) { yb[c][p] = yc[c][p+2]; ob[c][p] = oc[c][p+2]; }
}

template<bool EDGE>
__device__ __forceinline__ void pairs_dy0(const float (&yc)[3][8], const float (&oc)[3][8],
                                          const bool (&cv)[8], float& acc)
{
    constexpr float L0[3] = { 0.f, -20.99717945f, -20.99435343f }; // [adx]
#pragma unroll
    for (int dx = 1; dx <= 2; ++dx) {
        const float L = L0[dx];
#pragma unroll
        for (int p = 0; p < 4; ++p) {
            const int k = p + dx + 2, kb = p + 2;
            const float d0 = yc[0][k] - yc[0][kb];
            const float d1 = yc[1][k] - yc[1][kb];
            const float d2 = yc[2][k] - yc[2][kb];
            const float ss = fmaf(d2, d2, fmaf(d1, d1, d0 * d0));
            const float sad = fabsf(oc[0][k] - oc[0][kb]) + fabsf(oc[1][k] - oc[1][kb])
                            + fabsf(oc[2][k] - oc[2][kb]);
            const float sadm = (!EDGE || cv[k]) ? sad : 0.f;
            acc = fmaf(EXP2(fmaf(SC2, ss, L)), sadm, acc);
        }
    }
}

template<int DY, bool EDGE>
__device__ __forceinline__ void pairs_dyn(const float (&yc)[3][8], const float (&oc)[3][8],
                                          const float (&yb)[3][4], const float (&ob)[3][4],
                                          const bool (&cv)[8], float& acc)
{
    constexpr float L1[3] = { -20.99717945f, -20.99435890f, -20.99153288f }; // dy=1,[adx]
    constexpr float L2[3] = { -20.99435343f, -20.99153288f, -20.98870686f }; // dy=2,[adx]
#pragma unroll
    for (int dx = -2; dx <= 2; ++dx) {
        const int adx = dx < 0 ? -dx : dx;
        const float L = (DY == 1) ? L1[adx] : L2[adx];
#pragma unroll
        for (int p = 0; p < 4; ++p) {
            const int k = p + dx + 2;              // 0..7
            const float d0 = yc[0][k] - yb[0][p];
            const float d1 = yc[1][k] - yb[1][p];
            const float d2 = yc[2][k] - yb[2][p];
            const float ss = fmaf(d2, d2, fmaf(d1, d1, d0 * d0));
            const float sad = fabsf(oc[0][k] - ob[0][p]) + fabsf(oc[1][k] - ob[1][p])
                            + fabsf(oc[2][k] - ob[2][p]);
            const float sadm = (!EDGE || cv[k]) ? sad : 0.f;
            acc = fmaf(EXP2(fmaf(SC2, ss, L)), sadm, acc);
        }
    }
}

template<bool EDGE>
__device__ __forceinline__ float run_strip(const float* __restrict__ x,
                                           const float* __restrict__ op,
                                           int wq, int rb, int b)
{
    bool cv[8];
#pragma unroll
    for (int k = 0; k < 8; ++k) cv[k] = !EDGE || ((unsigned)(wq - 2 + k) < (unsigned)WW);

    const int fb0 = (b * 3 * HH + rb) * WW + (wq - 4);   // c=0, s=0 window base
    int mrow = (2 * rb + wq + 2) % 3;                    // fb0 % 3 (nonneg form)

    float Rc[3][5], Rb[3];
    float yp[2][3][4], opv[2][3][4];
    float yc[3][8], oc[3][8];
    float acc0 = 0.f, acc1 = 0.f;

    // ---- s = 0 ----
    build_rot(mrow, Rc, Rb);
    load_make<EDGE>(x, op, fb0, Rc, Rb, yc, oc);
    pairs_dy0<EDGE>(yc, oc, cv, acc0);
    stash(yp[0], opv[0], yc, oc);
    // ---- s = 1 ----
    mrow = mod3s(mrow + 2);
    build_rot(mrow, Rc, Rb);
    load_make<EDGE>(x, op, fb0 + WW, Rc, Rb, yc, oc);
    pairs_dy0<EDGE>(yc, oc, cv, acc0);
    pairs_dyn<1, EDGE>(yc, oc, yp[0], opv[0], cv, acc1);
    stash(yp[1], opv[1], yc, oc);

#pragma unroll 1
    for (int s = 2; s < 10; s += 2) {
        // ---- row A = s: slot0 holds s-2, slot1 holds s-1 ----
        mrow = mod3s(mrow + 2);
        build_rot(mrow, Rc, Rb);
        const bool rokA = !EDGE || (rb + s) < HH;
        load_make<EDGE>(x, op, fb0 + s * WW, Rc, Rb, yc, oc);
        if (s < 8) pairs_dy0<EDGE>(yc, oc, cv, acc0);
        if (rokA) {
            pairs_dyn<1, EDGE>(yc, oc, yp[1], opv[1], cv, acc0);   // base row s-1
            pairs_dyn<2, EDGE>(yc, oc, yp[0], opv[0], cv, acc1);   // base row s-2
        }
        if (s < 8) stash(yp[0], opv[0], yc, oc);
        // ---- row B = s+1: slot0 holds s, slot1 holds s-1 ----
        mrow = mod3s(mrow + 2);
        build_rot(mrow, Rc, Rb);
        const bool rokB = !EDGE || (rb + s + 1) < HH;
        load_make<EDGE>(x, op, fb0 + (s + 1) * WW, Rc, Rb, yc, oc);
        if (s + 1 < 8) pairs_dy0<EDGE>(yc, oc, cv, acc0);
        if (rokB) {
            if (s < 8) pairs_dyn<1, EDGE>(yc, oc, yp[0], opv[0], cv, acc0);  // base row s
            pairs_dyn<2, EDGE>(yc, oc, yp[1], opv[1], cv, acc1);             // base row s-1
        }
        if (s + 1 < 8) stash(yp[1], opv[1], yc, oc);
    }

    return acc0 + acc1;
}

__global__ __launch_bounds__(256)
void smooth_loss_kernel(const float* __restrict__ x, const float* __restrict__ op,
                        float* __restrict__ total)
{
    const int tx  = threadIdx.x;                    // 0..31
    const int ty  = threadIdx.y;                    // 0..7
    const int tid = ty * 32 + tx;
    const int bx  = blockIdx.x, by = blockIdx.y, b = blockIdx.z;
    const int wq  = bx * 128 + 4 * tx;              // first owned col
    const int rb  = by * 64 + 8 * ty;               // first owned row (<= 504)

    // interior blocks (44%): windows never touch image edges -> no clamps/selects
    float acc;
    if ((bx == 1 || bx == 2) && by < 7)             // block-uniform branch
        acc = run_strip<false>(x, op, wq, rb, b);
    else
        acc = run_strip<true>(x, op, wq, rb, b);

    // ---- reduction: wave shuffle -> LDS -> one atomic per block ----
#pragma unroll
    for (int off = 32; off > 0; off >>= 1)
        acc += __shfl_down(acc, off, 64);

    __shared__ float s_part[4];
    if ((tid & 63) == 0) s_part[tid >> 6] = acc;
    __syncthreads();
    if (tid == 0)
        atomicAdd(total, s_part[0] + s_part[1] + s_part[2] + s_part[3]);
}

extern "C" void kernel_launch(void* const* d_in, const int* in_sizes, int n_in,
                              void* d_out, int out_size, void* d_ws, size_t ws_size,
                              hipStream_t stream) {
    const float* x  = (const float*)d_in[0];   // "input"  [16,3,512,512] fp32
    const float* op = (const float*)d_in[1];   // "output" [16,3,512,512] fp32
    float* total = (float*)d_out;              // scalar fp32

    hipMemsetAsync(total, 0, sizeof(float), stream);

    dim3 grid(4, 8, NB);                       // 512 blocks (2/CU)
    dim3 block(32, 8);                         // 256 threads; strip 4x8 each
    smooth_loss_kernel<<<grid, block, 0, stream>>>(x, op, total);
}